// Round 8
// baseline (52.741 us; speedup 1.0000x reference)
//
#include <hip/hip_runtime.h>

typedef __attribute__((ext_vector_type(4))) float f32x4;
typedef __attribute__((ext_vector_type(8))) short bf16x8;
typedef _Float16 f16x8 __attribute__((ext_vector_type(8)));

#define MFMA16(a, b, c) __builtin_amdgcn_mfma_f32_16x16x32_f16((a), (b), (c), 0, 0, 0)
#define MFMABF(a, b, c) __builtin_amdgcn_mfma_f32_16x16x32_bf16((a), (b), (c), 0, 0, 0)

constexpr size_t TILE_FRAG_BYTES = 8192;               // 64x64 fp16, frag-major
constexpr size_t NTILES = 512;                         // B*H*16
constexpr size_t ARR_S  = NTILES * TILE_FRAG_BYTES;    // 4 MiB (K or V array)
constexpr size_t PART_O_OFF  = 16u << 20;              // 1536 x 16 KiB O partials
constexpr size_t PART_ML_OFF = PART_O_OFF + 1536 * 16384;  // 1536 x 512 B m/l
constexpr size_t WS_NEED = PART_ML_OFF + 1536 * 512;

// Swizzled byte offset inside a 64-row x 64-col 2-byte-elem LDS tile/strip.
__device__ __forceinline__ int swz_off(int row, int col) {
    return (row * 128 + col * 2) ^ ((row & 7) << 4);
}
__device__ __forceinline__ f16x8 ld_frag16(const char* tile, int row, int col) {
    return *(const f16x8*)(tile + swz_off(row, col));
}

// ---------------------------------------------------------------------------
// Pre-pass (unchanged, verified): K -> fp16 fragment-major tiles (direct);
// V -> transposed fp16 fragment-major tiles (LDS transpose).
// ---------------------------------------------------------------------------
__global__ __launch_bounds__(256) void bigbird_prepass(
    const float* __restrict__ K, const float* __restrict__ V,
    char* __restrict__ ws) {
    __shared__ float vf[64][66];
    const int tile = blockIdx.x;
    const int tid  = threadIdx.x;
    const float* Kt = K + (size_t)tile * 4096;
    const float* Vt = V + (size_t)tile * 4096;
    f16x8* Ko = (f16x8*)(ws + (size_t)tile * TILE_FRAG_BYTES);
    f16x8* Vo = (f16x8*)(ws + ARR_S + (size_t)tile * TILE_FRAG_BYTES);

    {   // V: coalesced load into padded LDS (for transposed gather below)
        const int row = tid >> 2;
        const int c0  = (tid & 3) << 4;
        const float* p = Vt + row * 64 + c0;
        f32x4 e0 = *(const f32x4*)p,       e1 = *(const f32x4*)(p + 4),
              e2 = *(const f32x4*)(p + 8), e3 = *(const f32x4*)(p + 12);
#pragma unroll
        for (int e = 0; e < 4; ++e) {
            vf[row][c0 + e] = e0[e];     vf[row][c0 + 4 + e] = e1[e];
            vf[row][c0 + 8 + e] = e2[e]; vf[row][c0 + 12 + e] = e3[e];
        }
    }
    // K: direct global->convert->frag store (no LDS round trip).
#pragma unroll
    for (int t = 0; t < 2; ++t) {
        int s = tid + t * 256;
        int f = s >> 6, lane = s & 63;
        int j = f >> 1, kk = f & 1;
        int l16 = lane & 15, g = lane >> 4;
        const float* p = Kt + (j * 16 + l16) * 64 + kk * 32 + g * 8;
        f32x4 a = *(const f32x4*)p;
        f32x4 c = *(const f32x4*)(p + 4);
        f16x8 kv;
#pragma unroll
        for (int e = 0; e < 4; ++e) {
            kv[e]     = (_Float16)a[e];
            kv[4 + e] = (_Float16)c[e];
        }
        Ko[s] = kv;
    }
    __syncthreads();
#pragma unroll
    for (int t = 0; t < 2; ++t) {
        int s = tid + t * 256;
        int f = s >> 6, lane = s & 63;
        int j = f >> 1, kk = f & 1;
        int l16 = lane & 15, g = lane >> 4;
        f16x8 vv;
#pragma unroll
        for (int e = 0; e < 8; ++e)
            vv[e] = (_Float16)vf[kk * 32 + g * 8 + e][j * 16 + l16];
        Vo[s] = vv;
    }
}

// ---------------------------------------------------------------------------
// Chunk kernel: 1536 WGs = 512 row-blocks x 3 chunks of <=ceil(n/3) tiles.
// 4 waves = 4 row strips, free-running per-wave frag loads (no loop barriers).
// Writes unnormalized partial (O, m, l) per chunk.
// ---------------------------------------------------------------------------
__global__ __launch_bounds__(256) void bigbird_chunk(
    const float* __restrict__ Q, const float* __restrict__ M,
    char* __restrict__ ws) {
    constexpr int H = 16, F = 1024, D = 64;

    __shared__ char p_sm[4][2048];
    __shared__ int flags[16];
    __shared__ int list[16];
    __shared__ int ncnt;

    const int bid = blockIdx.x;
    const int rb  = bid & 511;          // canonical row-block id
    const int c   = bid >> 9;           // chunk 0..2
    const int bh  = rb >> 4;            // 0..31 = b*16+h
    const int fb  = rb & 15;
    const int b   = bh >> 4;
    const int h   = bh & 15;

    const int tid  = threadIdx.x;
    const int lane = tid & 63;
    const int w    = tid >> 6;
    const int g    = lane >> 4;
    const int l16  = lane & 15;

    if (tid < 16)
        flags[tid] = (M[((size_t)(h * 1024 + fb * 64)) * 1024 + tid * 64] > 0.5f) ? 1 : 0;
    __syncthreads();
    if (tid == 0) {
        int nn = 0;
        for (int t = 0; t < 16; ++t)
            if (flags[t]) list[nn++] = t;
        ncnt = nn;
    }
    __syncthreads();
    const int n = ncnt;
    const int s = (n + 2) / 3;
    const int beg = c * s;
    if (beg >= n) return;               // empty chunk, uniform exit
    const int end = min(beg + s, n);

    // Q A-fragments (fp16, x0.125) straight from global.
    f16x8 qf[2];
    {
        const float* qr = Q + ((size_t)bh * F + fb * 64 + w * 16 + l16) * D;
#pragma unroll
        for (int kk = 0; kk < 2; ++kk) {
            const float* p = qr + kk * 32 + g * 8;
            f32x4 a = *(const f32x4*)p;
            f32x4 cc = *(const f32x4*)(p + 4);
#pragma unroll
            for (int e = 0; e < 8; ++e)
                qf[kk][e] = (_Float16)((e < 4 ? a[e] : cc[e - 4]) * 0.125f);
        }
    }

    f32x4 acc[4];
    float m_r[4], l_r[4];
#pragma unroll
    for (int j = 0; j < 4; ++j) acc[j] = f32x4{0.f, 0.f, 0.f, 0.f};
#pragma unroll
    for (int r = 0; r < 4; ++r) { m_r[r] = -1e30f; l_r[r] = 0.f; }

    const f16x8* Kbase = (const f16x8*)ws + (size_t)bh * 16 * 512;
    const f16x8* Vbase = (const f16x8*)(ws + ARR_S) + (size_t)bh * 16 * 512;
    char* pw = p_sm[w];

    for (int i = beg; i < end; ++i) {
        const int tb = list[i];
        const f16x8* Kf = Kbase + (size_t)tb * 512;
        const f16x8* Vf = Vbase + (size_t)tb * 512;

        f16x8 kfr[4][2], vfr[4][2];
#pragma unroll
        for (int j = 0; j < 4; ++j)
#pragma unroll
            for (int kk = 0; kk < 2; ++kk) {
                kfr[j][kk] = Kf[(j * 2 + kk) * 64 + lane];
                vfr[j][kk] = Vf[(j * 2 + kk) * 64 + lane];
            }

        // S = Q K^T
        f32x4 sv[4];
#pragma unroll
        for (int j = 0; j < 4; ++j) {
            sv[j] = f32x4{0.f, 0.f, 0.f, 0.f};
#pragma unroll
            for (int kk = 0; kk < 2; ++kk)
                sv[j] = MFMA16(qf[kk], kfr[j][kk], sv[j]);
        }

        // Online softmax (rows g*4+r within strip, col j*16+l16).
        float rmax[4];
#pragma unroll
        for (int r = 0; r < 4; ++r)
            rmax[r] = fmaxf(fmaxf(sv[0][r], sv[1][r]), fmaxf(sv[2][r], sv[3][r]));
#pragma unroll
        for (int off = 1; off < 16; off <<= 1)
#pragma unroll
            for (int r = 0; r < 4; ++r)
                rmax[r] = fmaxf(rmax[r], __shfl_xor(rmax[r], off, 64));
        float alpha[4], psum[4];
#pragma unroll
        for (int r = 0; r < 4; ++r) {
            float mn = fmaxf(m_r[r], rmax[r]);
            alpha[r] = __expf(m_r[r] - mn);
            m_r[r]   = mn;
            psum[r]  = 0.f;
        }
#pragma unroll
        for (int j = 0; j < 4; ++j)
#pragma unroll
            for (int r = 0; r < 4; ++r) {
                float pe = __expf(sv[j][r] - m_r[r]);
                sv[j][r] = pe;
                psum[r] += pe;
            }
#pragma unroll
        for (int off = 1; off < 16; off <<= 1)
#pragma unroll
            for (int r = 0; r < 4; ++r)
                psum[r] += __shfl_xor(psum[r], off, 64);
#pragma unroll
        for (int r = 0; r < 4; ++r)
            l_r[r] = l_r[r] * alpha[r] + psum[r];
#pragma unroll
        for (int j = 0; j < 4; ++j)
#pragma unroll
            for (int r = 0; r < 4; ++r)
                acc[j][r] *= alpha[r];

        // P (fp16) -> wave-private LDS strip: C-layout -> A-frag reshape.
#pragma unroll
        for (int j = 0; j < 4; ++j)
#pragma unroll
            for (int r = 0; r < 4; ++r)
                *(_Float16*)(pw + swz_off(g * 4 + r, j * 16 + l16)) = (_Float16)sv[j][r];
        asm volatile("s_waitcnt lgkmcnt(0)" ::: "memory");
        __builtin_amdgcn_sched_barrier(0);

        // O += P * V
#pragma unroll
        for (int kk = 0; kk < 2; ++kk) {
            f16x8 pa = ld_frag16(pw, l16, kk * 32 + g * 8);
#pragma unroll
            for (int jd = 0; jd < 4; ++jd)
                acc[jd] = MFMA16(pa, vfr[jd][kk], acc[jd]);
        }
    }

    // Write unnormalized partial (O, m, l) for this chunk.
    float* Op = (float*)(ws + PART_O_OFF + (size_t)(rb * 3 + c) * 16384);
    float* ml = (float*)(ws + PART_ML_OFF + (size_t)(rb * 3 + c) * 512);
#pragma unroll
    for (int r = 0; r < 4; ++r) {
        int row = w * 16 + g * 4 + r;
#pragma unroll
        for (int j = 0; j < 4; ++j)
            Op[row * 64 + j * 16 + l16] = acc[j][r];
        if (l16 == 0) {
            ml[row]      = m_r[r];
            ml[64 + row] = l_r[r];
        }
    }
}

// ---------------------------------------------------------------------------
// Combine: 512 WGs, one per row-block. Merges <=3 chunk partials exactly
// in f32, writes Out [B, F, H, D].
// ---------------------------------------------------------------------------
__global__ __launch_bounds__(256) void bigbird_combine(
    const float* __restrict__ M, const char* __restrict__ ws,
    float* __restrict__ Out) {
    constexpr int H = 16, F = 1024, D = 64;
    __shared__ int flags[16];
    __shared__ int ncnt;

    const int rb = blockIdx.x;
    const int bh = rb >> 4;
    const int fb = rb & 15;
    const int b  = bh >> 4;
    const int h  = bh & 15;
    const int tid = threadIdx.x;
    const int row = tid >> 2;          // 0..63
    const int q4  = tid & 3;           // 16-col slice

    if (tid < 16)
        flags[tid] = (M[((size_t)(h * 1024 + fb * 64)) * 1024 + tid * 64] > 0.5f) ? 1 : 0;
    __syncthreads();
    if (tid == 0) {
        int nn = 0;
        for (int t = 0; t < 16; ++t) nn += flags[t];
        ncnt = nn;
    }
    __syncthreads();
    const int n = ncnt;
    const int s = (n + 2) / 3;

    const char* Obase  = ws + PART_O_OFF  + (size_t)rb * 3 * 16384;
    const char* mlbase = ws + PART_ML_OFF + (size_t)rb * 3 * 512;

    float Mx = -1e30f;
#pragma unroll
    for (int c = 0; c < 3; ++c)
        if (c * s < n)
            Mx = fmaxf(Mx, ((const float*)(mlbase + c * 512))[row]);

    float L = 0.f;
    f32x4 o[4] = { f32x4{0,0,0,0}, f32x4{0,0,0,0}, f32x4{0,0,0,0}, f32x4{0,0,0,0} };
#pragma unroll
    for (int c = 0; c < 3; ++c)
        if (c * s < n) {
            const float* ml = (const float*)(mlbase + c * 512);
            float wgt = __expf(ml[row] - Mx);
            L += ml[64 + row] * wgt;
            const float* Op = (const float*)(Obase + c * 16384) + row * 64 + q4 * 16;
#pragma unroll
            for (int q = 0; q < 4; ++q) {
                f32x4 v = *(const f32x4*)(Op + q * 4);
#pragma unroll
                for (int e = 0; e < 4; ++e) o[q][e] += v[e] * wgt;
            }
        }

    float invL = 1.0f / L;
    int f = fb * 64 + row;
    float* ob = Out + ((size_t)(b * F + f) * H + h) * D + q4 * 16;
#pragma unroll
    for (int q = 0; q < 4; ++q) {
        f32x4 v;
#pragma unroll
        for (int e = 0; e < 4; ++e) v[e] = o[q][e] * invL;
        *(f32x4*)(ob + q * 4) = v;
    }
}

// ---------------------------------------------------------------------------
// Fallback (verified R0-style kernel): used only if ws is too small.
// ---------------------------------------------------------------------------
__device__ __forceinline__ unsigned short f2bf(float x) {
    unsigned u = __builtin_bit_cast(unsigned, x);
    unsigned r = u + 0x7fffu + ((u >> 16) & 1u);
    return (unsigned short)(r >> 16);
}
__device__ __forceinline__ float bf2f(unsigned short h) {
    return __builtin_bit_cast(float, (unsigned)h << 16);
}
__device__ __forceinline__ bf16x8 ld_fragb(const char* tile, int row, int col) {
    return *(const bf16x8*)(tile + swz_off(row, col));
}
__device__ __forceinline__ void stage_rm_fb(const float* __restrict__ src,
                                            char* hi_t, char* lo_t, float scale) {
    const int tid = threadIdx.x;
    const int row = tid >> 2;
    const int c0  = (tid & 3) << 4;
    const float* p = src + row * 64 + c0;
    f32x4 vv[4] = { *(const f32x4*)(p), *(const f32x4*)(p + 4),
                    *(const f32x4*)(p + 8), *(const f32x4*)(p + 12) };
    bf16x8 h2[2], l2[2];
#pragma unroll
    for (int e = 0; e < 16; ++e) {
        float x = vv[e >> 2][e & 3] * scale;
        unsigned short hb = f2bf(x);
        unsigned short lb = f2bf(x - bf2f(hb));
        h2[e >> 3][e & 7] = (short)hb;
        l2[e >> 3][e & 7] = (short)lb;
    }
#pragma unroll
    for (int gi = 0; gi < 2; ++gi) {
        int off = swz_off(row, c0 + gi * 8);
        *(bf16x8*)(hi_t + off) = h2[gi];
        *(bf16x8*)(lo_t + off) = l2[gi];
    }
}
__device__ __forceinline__ void stage_tr_fb(const float* __restrict__ src,
                                            char* hi_t, char* lo_t) {
    const int tid = threadIdx.x;
    const int t  = tid >> 2;
    const int c0 = (tid & 3) << 4;
    const float* p = src + t * 64 + c0;
    f32x4 vv[4] = { *(const f32x4*)(p), *(const f32x4*)(p + 4),
                    *(const f32x4*)(p + 8), *(const f32x4*)(p + 12) };
#pragma unroll
    for (int e = 0; e < 16; ++e) {
        float x = vv[e >> 2][e & 3];
        unsigned short hb = f2bf(x);
        unsigned short lb = f2bf(x - bf2f(hb));
        int d = c0 + e;
        int off = (d * 128 + t * 2) ^ ((d & 7) << 4);
        *(unsigned short*)(hi_t + off) = hb;
        *(unsigned short*)(lo_t + off) = lb;
    }
}
__global__ __launch_bounds__(256) void bigbird_kernel_fb(
    const float* __restrict__ Q, const float* __restrict__ K,
    const float* __restrict__ V, const float* __restrict__ M,
    float* __restrict__ Out) {
    constexpr int H = 16, F = 1024, D = 64;
    __shared__ char kq_hi[8192];
    __shared__ char kq_lo[8192];
    __shared__ char vt_hi[8192];
    __shared__ char vt_lo[8192];
    __shared__ char p_smf[8192];
    __shared__ int flags[16];
    const int bid = blockIdx.x;
    const int fb  = bid & 15;
    const int h   = (bid >> 4) & 15;
    const int b   = bid >> 8;
    const int tid  = threadIdx.x;
    const int lane = tid & 63;
    const int w    = tid >> 6;
    const int g    = lane >> 4;
    const int l16  = lane & 15;
    if (tid < 16)
        flags[tid] = (M[(h * 1024 + fb * 64) * 1024 + tid * 64] > 0.5f) ? 1 : 0;
    const float* qb = Q + ((size_t)(b * H + h) * F + fb * 64) * D;
    stage_rm_fb(qb, kq_hi, kq_lo, 0.125f);
    __syncthreads();
    bf16x8 qh[2], ql[2];
#pragma unroll
    for (int kk = 0; kk < 2; ++kk) {
        qh[kk] = ld_fragb(kq_hi, w * 16 + l16, kk * 32 + g * 8);
        ql[kk] = ld_fragb(kq_lo, w * 16 + l16, kk * 32 + g * 8);
    }
    f32x4 acc[4];
    float m_r[4], l_r[4];
#pragma unroll
    for (int j = 0; j < 4; ++j) acc[j] = f32x4{0.f, 0.f, 0.f, 0.f};
#pragma unroll
    for (int r = 0; r < 4; ++r) { m_r[r] = -1e30f; l_r[r] = 0.f; }
    const float* kb = K + (size_t)(b * H + h) * 1024 * D;
    const float* vb = V + (size_t)(b * H + h) * 1024 * D;
    for (int tb = 0; tb < 16; ++tb) {
        if (!flags[tb]) continue;
        __syncthreads();
        stage_rm_fb(kb + tb * 64 * D, kq_hi, kq_lo, 1.0f);
        stage_tr_fb(vb + tb * 64 * D, vt_hi, vt_lo);
        __syncthreads();
        f32x4 s[4];
#pragma unroll
        for (int j = 0; j < 4; ++j) {
            s[j] = f32x4{0.f, 0.f, 0.f, 0.f};
#pragma unroll
            for (int kk = 0; kk < 2; ++kk) {
                bf16x8 bhf = ld_fragb(kq_hi, j * 16 + l16, kk * 32 + g * 8);
                bf16x8 blf = ld_fragb(kq_lo, j * 16 + l16, kk * 32 + g * 8);
                s[j] = MFMABF(qh[kk], bhf, s[j]);
                s[j] = MFMABF(qh[kk], blf, s[j]);
                s[j] = MFMABF(ql[kk], bhf, s[j]);
            }
        }
        float rmax[4];
#pragma unroll
        for (int r = 0; r < 4; ++r)
            rmax[r] = fmaxf(fmaxf(s[0][r], s[1][r]), fmaxf(s[2][r], s[3][r]));
#pragma unroll
        for (int off = 1; off < 16; off <<= 1)
#pragma unroll
            for (int r = 0; r < 4; ++r)
                rmax[r] = fmaxf(rmax[r], __shfl_xor(rmax[r], off, 64));
        float alpha[4], psum[4];
#pragma unroll
        for (int r = 0; r < 4; ++r) {
            float mn = fmaxf(m_r[r], rmax[r]);
            alpha[r] = __expf(m_r[r] - mn);
            m_r[r]   = mn;
            psum[r]  = 0.f;
        }
#pragma unroll
        for (int j = 0; j < 4; ++j)
#pragma unroll
            for (int r = 0; r < 4; ++r) {
                float pe = __expf(s[j][r] - m_r[r]);
                s[j][r] = pe;
                psum[r] += pe;
            }
#pragma unroll
        for (int off = 1; off < 16; off <<= 1)
#pragma unroll
            for (int r = 0; r < 4; ++r)
                psum[r] += __shfl_xor(psum[r], off, 64);
#pragma unroll
        for (int r = 0; r < 4; ++r)
            l_r[r] = l_r[r] * alpha[r] + psum[r];
#pragma unroll
        for (int j = 0; j < 4; ++j)
#pragma unroll
            for (int r = 0; r < 4; ++r)
                acc[j][r] *= alpha[r];
#pragma unroll
        for (int j = 0; j < 4; ++j)
#pragma unroll
            for (int r = 0; r < 4; ++r) {
                int row = w * 16 + g * 4 + r;
                *(unsigned short*)(p_smf + swz_off(row, j * 16 + l16)) = f2bf(s[j][r]);
            }
        __syncthreads();
#pragma unroll
        for (int kk = 0; kk < 2; ++kk) {
            bf16x8 pa = ld_fragb(p_smf, w * 16 + l16, kk * 32 + g * 8);
#pragma unroll
            for (int jd = 0; jd < 4; ++jd) {
                bf16x8 vh = ld_fragb(vt_hi, jd * 16 + l16, kk * 32 + g * 8);
                bf16x8 vl = ld_fragb(vt_lo, jd * 16 + l16, kk * 32 + g * 8);
                acc[jd] = MFMABF(pa, vh, acc[jd]);
                acc[jd] = MFMABF(pa, vl, acc[jd]);
            }
        }
    }
#pragma unroll
    for (int r = 0; r < 4; ++r) {
        float inv = 1.0f / l_r[r];
        int f = fb * 64 + w * 16 + g * 4 + r;
        float* ob = Out + ((size_t)(b * F + f) * H + h) * D;
#pragma unroll
        for (int jd = 0; jd < 4; ++jd)
            ob[jd * 16 + l16] = acc[jd][r] * inv;
    }
}

extern "C" void kernel_launch(void* const* d_in, const int* in_sizes, int n_in,
                              void* d_out, int out_size, void* d_ws, size_t ws_size,
                              hipStream_t stream) {
    const float* q = (const float*)d_in[0];
    const float* k = (const float*)d_in[1];
    const float* v = (const float*)d_in[2];
    const float* m = (const float*)d_in[3];
    float* out = (float*)d_out;
    if (ws_size >= WS_NEED) {
        bigbird_prepass<<<dim3(512), dim3(256), 0, stream>>>(k, v, (char*)d_ws);
        bigbird_chunk<<<dim3(1536), dim3(256), 0, stream>>>(q, m, (char*)d_ws);
        bigbird_combine<<<dim3(512), dim3(256), 0, stream>>>(m, (const char*)d_ws, out);
    } else {
        bigbird_kernel_fb<<<dim3(512), dim3(256), 0, stream>>>(q, k, v, m, out);
    }
}

// Round 9
// 41.596 us; speedup vs baseline: 1.2679x; 1.2679x over previous
//
#include <hip/hip_runtime.h>

typedef __attribute__((ext_vector_type(4))) float f32x4;
typedef __attribute__((ext_vector_type(8))) short bf16x8;
typedef _Float16 f16x8 __attribute__((ext_vector_type(8)));

#define MFMA16(a, b, c) __builtin_amdgcn_mfma_f32_16x16x32_f16((a), (b), (c), 0, 0, 0)
#define MFMABF(a, b, c) __builtin_amdgcn_mfma_f32_16x16x32_bf16((a), (b), (c), 0, 0, 0)

constexpr size_t TILE_FRAG_BYTES = 8192;               // 64x64 fp16, frag-major
constexpr size_t NTILES = 512;                         // B*H*16
constexpr size_t ARR_S  = NTILES * TILE_FRAG_BYTES;    // 4 MiB (K or V array)
constexpr size_t WS_NEED = 2 * ARR_S;                  // Kfrag + Vfrag

// Swizzled byte offset inside a 64-row x 64-col 2-byte-elem LDS tile/strip.
__device__ __forceinline__ int swz_off(int row, int col) {
    return (row * 128 + col * 2) ^ ((row & 7) << 4);
}
__device__ __forceinline__ f16x8 ld_frag16(const char* tile, int row, int col) {
    return *(const f16x8*)(tile + swz_off(row, col));
}

// ---------------------------------------------------------------------------
// Pre-pass (unchanged, verified): K -> fp16 fragment-major tiles (direct);
// V -> transposed fp16 fragment-major tiles (LDS transpose).
// Frag f=(j*2+kk), lane=g*16+l16:
//   K-frag elem e = K[j*16+l16][kk*32+g*8+e]      (B-frag for QK^T)
//   V-frag elem e = V[kk*32+g*8+e][j*16+l16]      (B-frag for PV, V^T)
// ---------------------------------------------------------------------------
__global__ __launch_bounds__(256) void bigbird_prepass(
    const float* __restrict__ K, const float* __restrict__ V,
    char* __restrict__ ws) {
    __shared__ float vf[64][66];
    const int tile = blockIdx.x;
    const int tid  = threadIdx.x;
    const float* Kt = K + (size_t)tile * 4096;
    const float* Vt = V + (size_t)tile * 4096;
    f16x8* Ko = (f16x8*)(ws + (size_t)tile * TILE_FRAG_BYTES);
    f16x8* Vo = (f16x8*)(ws + ARR_S + (size_t)tile * TILE_FRAG_BYTES);

    {   // V: coalesced load into padded LDS (for transposed gather below)
        const int row = tid >> 2;
        const int c0  = (tid & 3) << 4;
        const float* p = Vt + row * 64 + c0;
        f32x4 e0 = *(const f32x4*)p,       e1 = *(const f32x4*)(p + 4),
              e2 = *(const f32x4*)(p + 8), e3 = *(const f32x4*)(p + 12);
#pragma unroll
        for (int e = 0; e < 4; ++e) {
            vf[row][c0 + e] = e0[e];     vf[row][c0 + 4 + e] = e1[e];
            vf[row][c0 + 8 + e] = e2[e]; vf[row][c0 + 12 + e] = e3[e];
        }
    }
    // K: direct global->convert->frag store (no LDS round trip).
#pragma unroll
    for (int t = 0; t < 2; ++t) {
        int s = tid + t * 256;
        int f = s >> 6, lane = s & 63;
        int j = f >> 1, kk = f & 1;
        int l16 = lane & 15, g = lane >> 4;
        const float* p = Kt + (j * 16 + l16) * 64 + kk * 32 + g * 8;
        f32x4 a = *(const f32x4*)p;
        f32x4 c = *(const f32x4*)(p + 4);
        f16x8 kv;
#pragma unroll
        for (int e = 0; e < 4; ++e) {
            kv[e]     = (_Float16)a[e];
            kv[4 + e] = (_Float16)c[e];
        }
        Ko[s] = kv;
    }
    __syncthreads();
#pragma unroll
    for (int t = 0; t < 2; ++t) {
        int s = tid + t * 256;
        int f = s >> 6, lane = s & 63;
        int j = f >> 1, kk = f & 1;
        int l16 = lane & 15, g = lane >> 4;
        f16x8 vv;
#pragma unroll
        for (int e = 0; e < 8; ++e)
            vv[e] = (_Float16)vf[kk * 32 + g * 8 + e][j * 16 + l16];
        Vo[s] = vv;
    }
}

// ---------------------------------------------------------------------------
// Main: one WG per (b,h,64-row block); 4 waves = 4 row strips, free-running.
// TWO-PASS fixed-max softmax: pass 1 finds per-row max (no cross-lane ops in
// loop, no rescale); pass 2 recomputes QK^T and accumulates exp/PV against
// the FIXED max (no in-loop reduces, no acc rescale). Cross-lane shuffles run
// exactly twice, outside the loops.
// ---------------------------------------------------------------------------
__global__ __launch_bounds__(256) void bigbird_main(
    const float* __restrict__ Q, const float* __restrict__ M,
    const char* __restrict__ ws, float* __restrict__ Out) {
    constexpr int H = 16, F = 1024, D = 64;

    __shared__ char p_sm[4][2048];      // per-wave 16-row P strip
    __shared__ int flags[16];
    __shared__ int list[16];
    __shared__ int ncnt;

    // XCD-grouped remap: all 16 row-blocks of one (b,h) on one XCD.
    const int i0  = blockIdx.x;         // 0..511
    const int xcd = i0 & 7;
    const int q0  = i0 >> 3;            // 0..63
    const int grp = xcd * 4 + (q0 >> 4);// 0..31 == b*16+h
    const int fb  = q0 & 15;            // 64-row block
    const int b   = grp >> 4;
    const int h   = grp & 15;
    const int bh  = grp;

    const int tid  = threadIdx.x;
    const int lane = tid & 63;
    const int w    = tid >> 6;          // row strip 0..3
    const int g    = lane >> 4;
    const int l16  = lane & 15;

    if (tid < 16)
        flags[tid] = (M[((size_t)(h * 1024 + fb * 64)) * 1024 + tid * 64] > 0.5f) ? 1 : 0;

    // Q A-fragments (fp16, x0.125) straight from global.
    f16x8 qf[2];
    {
        const float* qr = Q + ((size_t)bh * F + fb * 64 + w * 16 + l16) * D;
#pragma unroll
        for (int kk = 0; kk < 2; ++kk) {
            const float* p = qr + kk * 32 + g * 8;
            f32x4 a = *(const f32x4*)p;
            f32x4 c = *(const f32x4*)(p + 4);
#pragma unroll
            for (int e = 0; e < 8; ++e)
                qf[kk][e] = (_Float16)((e < 4 ? a[e] : c[e - 4]) * 0.125f);
        }
    }
    __syncthreads();
    if (tid == 0) {
        int nn = 0;
        for (int t = 0; t < 16; ++t)
            if (flags[t]) list[nn++] = t;
        ncnt = nn;
    }
    __syncthreads();
    const int n = ncnt;

    const f16x8* Kbase = (const f16x8*)ws + (size_t)bh * 16 * 512;
    const f16x8* Vbase = (const f16x8*)(ws + ARR_S) + (size_t)bh * 16 * 512;
    char* pw = p_sm[w];

    // ---------------- Pass 1: per-row max (no cross-lane in loop) ----------
    float mrow[4];
#pragma unroll
    for (int r = 0; r < 4; ++r) mrow[r] = -1e30f;

    for (int i = 0; i < n; ++i) {
        const f16x8* Kf = Kbase + (size_t)list[i] * 512;
        f16x8 kfr[4][2];
#pragma unroll
        for (int j = 0; j < 4; ++j)
#pragma unroll
            for (int kk = 0; kk < 2; ++kk)
                kfr[j][kk] = Kf[(j * 2 + kk) * 64 + lane];
        f32x4 sv[4];
#pragma unroll
        for (int j = 0; j < 4; ++j) {
            sv[j] = f32x4{0.f, 0.f, 0.f, 0.f};
#pragma unroll
            for (int kk = 0; kk < 2; ++kk)
                sv[j] = MFMA16(qf[kk], kfr[j][kk], sv[j]);
        }
#pragma unroll
        for (int r = 0; r < 4; ++r)
            mrow[r] = fmaxf(mrow[r],
                      fmaxf(fmaxf(sv[0][r], sv[1][r]), fmaxf(sv[2][r], sv[3][r])));
    }
    // One-shot 16-lane reduce (stays within l16 group).
#pragma unroll
    for (int off = 1; off < 16; off <<= 1)
#pragma unroll
        for (int r = 0; r < 4; ++r)
            mrow[r] = fmaxf(mrow[r], __shfl_xor(mrow[r], off, 64));

    // ---------------- Pass 2: exp with fixed max + PV ----------------------
    f32x4 acc[4];
    float lsum[4];
#pragma unroll
    for (int j = 0; j < 4; ++j) acc[j] = f32x4{0.f, 0.f, 0.f, 0.f};
#pragma unroll
    for (int r = 0; r < 4; ++r) lsum[r] = 0.f;

    for (int i = 0; i < n; ++i) {
        const int tb = list[i];
        const f16x8* Kf = Kbase + (size_t)tb * 512;
        const f16x8* Vf = Vbase + (size_t)tb * 512;
        f16x8 kfr[4][2], vfr[4][2];
#pragma unroll
        for (int j = 0; j < 4; ++j)
#pragma unroll
            for (int kk = 0; kk < 2; ++kk) {
                kfr[j][kk] = Kf[(j * 2 + kk) * 64 + lane];
                vfr[j][kk] = Vf[(j * 2 + kk) * 64 + lane];
            }
        f32x4 sv[4];
#pragma unroll
        for (int j = 0; j < 4; ++j) {
            sv[j] = f32x4{0.f, 0.f, 0.f, 0.f};
#pragma unroll
            for (int kk = 0; kk < 2; ++kk)
                sv[j] = MFMA16(qf[kk], kfr[j][kk], sv[j]);
        }
        // exp against fixed max: fully lane-local, no reduce, no rescale.
#pragma unroll
        for (int j = 0; j < 4; ++j)
#pragma unroll
            for (int r = 0; r < 4; ++r) {
                float pe = __expf(sv[j][r] - mrow[r]);
                sv[j][r] = pe;
                lsum[r] += pe;
            }
        // P (fp16) -> wave-private LDS strip: C-layout -> A-frag reshape.
#pragma unroll
        for (int j = 0; j < 4; ++j)
#pragma unroll
            for (int r = 0; r < 4; ++r)
                *(_Float16*)(pw + swz_off(g * 4 + r, j * 16 + l16)) = (_Float16)sv[j][r];
        asm volatile("s_waitcnt lgkmcnt(0)" ::: "memory");
        __builtin_amdgcn_sched_barrier(0);
        // O += P * V
#pragma unroll
        for (int kk = 0; kk < 2; ++kk) {
            f16x8 pa = ld_frag16(pw, l16, kk * 32 + g * 8);
#pragma unroll
            for (int jd = 0; jd < 4; ++jd)
                acc[jd] = MFMA16(pa, vfr[jd][kk], acc[jd]);
        }
    }

    // One-shot l reduce (cols split across the 16-lane group).
#pragma unroll
    for (int off = 1; off < 16; off <<= 1)
#pragma unroll
        for (int r = 0; r < 4; ++r)
            lsum[r] += __shfl_xor(lsum[r], off, 64);

    // Epilogue: normalize, write [B, F, H, D].
#pragma unroll
    for (int r = 0; r < 4; ++r) {
        float inv = 1.0f / lsum[r];
        int f = fb * 64 + w * 16 + g * 4 + r;
        float* ob = Out + ((size_t)(b * F + f) * H + h) * D;
#pragma unroll
        for (int jd = 0; jd < 4; ++jd)
            ob[jd * 16 + l16] = acc[jd][r] * inv;
    }
}

// ---------------------------------------------------------------------------
// Fallback (verified R0-style kernel): used only if ws is too small.
// ---------------------------------------------------------------------------
__device__ __forceinline__ unsigned short f2bf(float x) {
    unsigned u = __builtin_bit_cast(unsigned, x);
    unsigned r = u + 0x7fffu + ((u >> 16) & 1u);
    return (unsigned short)(r >> 16);
}
__device__ __forceinline__ float bf2f(unsigned short h) {
    return __builtin_bit_cast(float, (unsigned)h << 16);
}
__device__ __forceinline__ bf16x8 ld_fragb(const char* tile, int row, int col) {
    return *(const bf16x8*)(tile + swz_off(row, col));
}
__device__ __forceinline__ void stage_rm_fb(const float* __restrict__ src,
                                            char* hi_t, char* lo_t, float scale) {
    const int tid = threadIdx.x;
    const int row = tid >> 2;
    const int c0  = (tid & 3) << 4;
    const float* p = src + row * 64 + c0;
    f32x4 vv[4] = { *(const f32x4*)(p), *(const f32x4*)(p + 4),
                    *(const f32x4*)(p + 8), *(const f32x4*)(p + 12) };
    bf16x8 h2[2], l2[2];
#pragma unroll
    for (int e = 0; e < 16; ++e) {
        float x = vv[e >> 2][e & 3] * scale;
        unsigned short hb = f2bf(x);
        unsigned short lb = f2bf(x - bf2f(hb));
        h2[e >> 3][e & 7] = (short)hb;
        l2[e >> 3][e & 7] = (short)lb;
    }
#pragma unroll
    for (int gi = 0; gi < 2; ++gi) {
        int off = swz_off(row, c0 + gi * 8);
        *(bf16x8*)(hi_t + off) = h2[gi];
        *(bf16x8*)(lo_t + off) = l2[gi];
    }
}
__device__ __forceinline__ void stage_tr_fb(const float* __restrict__ src,
                                            char* hi_t, char* lo_t) {
    const int tid = threadIdx.x;
    const int t  = tid >> 2;
    const int c0 = (tid & 3) << 4;
    const float* p = src + t * 64 + c0;
    f32x4 vv[4] = { *(const f32x4*)(p), *(const f32x4*)(p + 4),
                    *(const f32x4*)(p + 8), *(const f32x4*)(p + 12) };
#pragma unroll
    for (int e = 0; e < 16; ++e) {
        float x = vv[e >> 2][e & 3];
        unsigned short hb = f2bf(x);
        unsigned short lb = f2bf(x - bf2f(hb));
        int d = c0 + e;
        int off = (d * 128 + t * 2) ^ ((d & 7) << 4);
        *(unsigned short*)(hi_t + off) = hb;
        *(unsigned short*)(lo_t + off) = lb;
    }
}
__global__ __launch_bounds__(256) void bigbird_kernel_fb(
    const float* __restrict__ Q, const float* __restrict__ K,
    const float* __restrict__ V, const float* __restrict__ M,
    float* __restrict__ Out) {
    constexpr int H = 16, F = 1024, D = 64;
    __shared__ char kq_hi[8192];
    __shared__ char kq_lo[8192];
    __shared__ char vt_hi[8192];
    __shared__ char vt_lo[8192];
    __shared__ char p_smf[8192];
    __shared__ int flags[16];
    const int bid = blockIdx.x;
    const int fb  = bid & 15;
    const int h   = (bid >> 4) & 15;
    const int b   = bid >> 8;
    const int tid  = threadIdx.x;
    const int lane = tid & 63;
    const int w    = tid >> 6;
    const int g    = lane >> 4;
    const int l16  = lane & 15;
    if (tid < 16)
        flags[tid] = (M[(h * 1024 + fb * 64) * 1024 + tid * 64] > 0.5f) ? 1 : 0;
    const float* qb = Q + ((size_t)(b * H + h) * F + fb * 64) * D;
    stage_rm_fb(qb, kq_hi, kq_lo, 0.125f);
    __syncthreads();
    bf16x8 qh[2], ql[2];
#pragma unroll
    for (int kk = 0; kk < 2; ++kk) {
        qh[kk] = ld_fragb(kq_hi, w * 16 + l16, kk * 32 + g * 8);
        ql[kk] = ld_fragb(kq_lo, w * 16 + l16, kk * 32 + g * 8);
    }
    f32x4 acc[4];
    float m_r[4], l_r[4];
#pragma unroll
    for (int j = 0; j < 4; ++j) acc[j] = f32x4{0.f, 0.f, 0.f, 0.f};
#pragma unroll
    for (int r = 0; r < 4; ++r) { m_r[r] = -1e30f; l_r[r] = 0.f; }
    const float* kb = K + (size_t)(b * H + h) * 1024 * D;
    const float* vb = V + (size_t)(b * H + h) * 1024 * D;
    for (int tb = 0; tb < 16; ++tb) {
        if (!flags[tb]) continue;
        __syncthreads();
        stage_rm_fb(kb + tb * 64 * D, kq_hi, kq_lo, 1.0f);
        stage_tr_fb(vb + tb * 64 * D, vt_hi, vt_lo);
        __syncthreads();
        f32x4 s[4];
#pragma unroll
        for (int j = 0; j < 4; ++j) {
            s[j] = f32x4{0.f, 0.f, 0.f, 0.f};
#pragma unroll
            for (int kk = 0; kk < 2; ++kk) {
                bf16x8 bhf = ld_fragb(kq_hi, j * 16 + l16, kk * 32 + g * 8);
                bf16x8 blf = ld_fragb(kq_lo, j * 16 + l16, kk * 32 + g * 8);
                s[j] = MFMABF(qh[kk], bhf, s[j]);
                s[j] = MFMABF(qh[kk], blf, s[j]);
                s[j] = MFMABF(ql[kk], bhf, s[j]);
            }
        }
        float rmax[4];
#pragma unroll
        for (int r = 0; r < 4; ++r)
            rmax[r] = fmaxf(fmaxf(s[0][r], s[1][r]), fmaxf(s[2][r], s[3][r]));
#pragma unroll
        for (int off = 1; off < 16; off <<= 1)
#pragma unroll
            for (int r = 0; r < 4; ++r)
                rmax[r] = fmaxf(rmax[r], __shfl_xor(rmax[r], off, 64));
        float alpha[4], psum[4];
#pragma unroll
        for (int r = 0; r < 4; ++r) {
            float mn = fmaxf(m_r[r], rmax[r]);
            alpha[r] = __expf(m_r[r] - mn);
            m_r[r]   = mn;
            psum[r]  = 0.f;
        }
#pragma unroll
        for (int j = 0; j < 4; ++j)
#pragma unroll
            for (int r = 0; r < 4; ++r) {
                float pe = __expf(s[j][r] - m_r[r]);
                s[j][r] = pe;
                psum[r] += pe;
            }
#pragma unroll
        for (int off = 1; off < 16; off <<= 1)
#pragma unroll
            for (int r = 0; r < 4; ++r)
                psum[r] += __shfl_xor(psum[r], off, 64);
#pragma unroll
        for (int r = 0; r < 4; ++r)
            l_r[r] = l_r[r] * alpha[r] + psum[r];
#pragma unroll
        for (int j = 0; j < 4; ++j)
#pragma unroll
            for (int r = 0; r < 4; ++r)
                acc[j][r] *= alpha[r];
#pragma unroll
        for (int j = 0; j < 4; ++j)
#pragma unroll
            for (int r = 0; r < 4; ++r) {
                int row = w * 16 + g * 4 + r;
                *(unsigned short*)(p_smf + swz_off(row, j * 16 + l16)) = f2bf(s[j][r]);
            }
        __syncthreads();
#pragma unroll
        for (int kk = 0; kk < 2; ++kk) {
            bf16x8 pa = ld_fragb(p_smf, w * 16 + l16, kk * 32 + g * 8);
#pragma unroll
            for (int jd = 0; jd < 4; ++jd) {
                bf16x8 vh = ld_fragb(vt_hi, jd * 16 + l16, kk * 32 + g * 8);
                bf16x8 vl = ld_fragb(vt_lo, jd * 16 + l16, kk * 32 + g * 8);
                acc[jd] = MFMABF(pa, vh, acc[jd]);
                acc[jd] = MFMABF(pa, vl, acc[jd]);
            }
        }
    }
#pragma unroll
    for (int r = 0; r < 4; ++r) {
        float inv = 1.0f / l_r[r];
        int f = fb * 64 + w * 16 + g * 4 + r;
        float* ob = Out + ((size_t)(b * F + f) * H + h) * D;
#pragma unroll
        for (int jd = 0; jd < 4; ++jd)
            ob[jd * 16 + l16] = acc[jd][r] * inv;
    }
}

extern "C" void kernel_launch(void* const* d_in, const int* in_sizes, int n_in,
                              void* d_out, int out_size, void* d_ws, size_t ws_size,
                              hipStream_t stream) {
    const float* q = (const float*)d_in[0];
    const float* k = (const float*)d_in[1];
    const float* v = (const float*)d_in[2];
    const float* m = (const float*)d_in[3];
    float* out = (float*)d_out;
    if (ws_size >= WS_NEED) {
        bigbird_prepass<<<dim3(512), dim3(256), 0, stream>>>(k, v, (char*)d_ws);
        bigbird_main<<<dim3(512), dim3(256), 0, stream>>>(q, m, (const char*)d_ws, out);
    } else {
        bigbird_kernel_fb<<<dim3(512), dim3(256), 0, stream>>>(q, k, v, m, out);
    }
}